// Round 15
// baseline (9780.672 us; speedup 1.0000x reference)
//
#include <hip/hip_runtime.h>

#define NR 512
#define NI 128
#define B 32
#define T 1000
#define KC 256   // OpenBLAS level3 driver K-panel rebalancing: K=512 -> [0,256)+[256,512)
#define G 64     // pipelined load-group width (double-buffered)
// Locked numeric model (verified PASS round 13):
//  - input GEMM: per element single ascending-i FMA chain.
//  - z @ w_rec_masked: two 256-wide ascending-k chains (panels [0,256)+[256,512)),
//    joined by one rounded add. Binary z => only active rows; masked diag and
//    zero-pads contribute exact +0 in-chain (s never hits -0: cancellation -> +0).
//  - elementwise: separate rounded f32 ops ((f32(decay)*v) + i_t) - z.

__device__ __forceinline__ float mul_nofma(float a, float b) {
    float r = a * b;
    asm volatile("" : "+v"(r));
    return r;
}

// ---------------- Kernel 0: masked w_rec copy + zero row into d_ws
// w_ws[r][u] = (r<NR && r!=u) ? w_rec[r][u] : 0 ; row NR is all zeros.
__global__ __launch_bounds__(512) void k_prep(const float* __restrict__ w_rec,
                                              float* __restrict__ w_ws) {
    const int r = blockIdx.x, u = threadIdx.x;
    float val = 0.f;
    if (r < NR && r != u) val = w_rec[r * NR + u];
    w_ws[r * NR + u] = val;
}

// ---------------- Kernel 1: i_in = inputs @ w_in -> voltages region of d_out
template <int ROWS>
__global__ __launch_bounds__(512) void k_in_gemm(const float* __restrict__ inputs,
                                                 const float* __restrict__ w_in,
                                                 float* __restrict__ i_in) {
    const int u = threadIdx.x;
    const int r0 = blockIdx.x * ROWS;
    float acc[ROWS];
#pragma unroll
    for (int r = 0; r < ROWS; ++r) acc[r] = 0.f;
    const float* __restrict__ inp = inputs + (long)r0 * NI;
#pragma unroll 4
    for (int i = 0; i < NI; ++i) {
        float w = w_in[i * NR + u];
#pragma unroll
        for (int r = 0; r < ROWS; ++r)
            acc[r] = __builtin_fmaf(inp[r * NI + i], w, acc[r]);   // ascending i, FMA
    }
#pragma unroll
    for (int r = 0; r < ROWS; ++r)
        i_in[(long)(r0 + r) * NR + u] = acc[r];
}

// ---- pipelined helpers (static indexing only; rule: no runtime-indexed arrays)
__device__ __forceinline__ void loadg(float (&buf)[G], const int* list, int k0,
                                      const float* __restrict__ w_ws, int u) {
#pragma unroll
    for (int qq = 0; qq < G / 4; ++qq) {
        int4 jv = *(const int4*)&list[k0 + qq * 4];
        int j0 = __builtin_amdgcn_readfirstlane(jv.x);
        int j1 = __builtin_amdgcn_readfirstlane(jv.y);
        int j2 = __builtin_amdgcn_readfirstlane(jv.z);
        int j3 = __builtin_amdgcn_readfirstlane(jv.w);
        buf[qq * 4 + 0] = w_ws[j0 * NR + u];
        buf[qq * 4 + 1] = w_ws[j1 * NR + u];
        buf[qq * 4 + 2] = w_ws[j2 * NR + u];
        buf[qq * 4 + 3] = w_ws[j3 * NR + u];
    }
}

__device__ __forceinline__ void sumg(const float (&buf)[G], int k0, int cnt_lo,
                                     float& s1, float& s2) {
    if (k0 + G <= cnt_lo) {
#pragma unroll
        for (int q = 0; q < G; ++q) s1 = __fadd_rn(s1, buf[q]);
    } else if (k0 >= cnt_lo) {
#pragma unroll
        for (int q = 0; q < G; ++q) s2 = __fadd_rn(s2, buf[q]);
    } else {
#pragma unroll
        for (int q = 0; q < G; ++q) {
            if (k0 + q < cnt_lo) s1 = __fadd_rn(s1, buf[q]);
            else                 s2 = __fadd_rn(s2, buf[q]);
        }
    }
}

// ---------------- Kernel 2: per-batch LIF scan, pipelined loads.
// 32 blocks x 512 threads; 2 barriers/step.
__global__ __launch_bounds__(512) void k_scan(const float* __restrict__ w_ws,
                                              const float* __restrict__ w_out,
                                              const float* __restrict__ b_out,
                                              float* __restrict__ out) {
    const int b = blockIdx.x;
    const int u = threadIdx.x;
    const int wav = u >> 6, lane = u & 63;

    float* __restrict__ volt_b = out + (long)b * (T * NR);                 // also i_in (in-place)
    float* __restrict__ spk_b  = out + (long)B * T * NR + (long)b * (T * NR);
    float* __restrict__ pred   = out + 2L * B * T * NR + (long)b * T;

    __shared__ __align__(16) int list[NR + G];
    __shared__ int wcnt[8];
    __shared__ double projp[8];

    if (u < G) list[NR + u] = NR;      // permanent pad -> zero row of w_ws

    float v = 0.f, z = 0.f;
    const float decay = 0.951229424500714f;   // f32 rounding of the python scalar
    const double wo = (double)w_out[u];
    const double bo = (double)b_out[0];
    double ema = 0.0;                          // thread 0's copy is canonical
    __syncthreads();

    for (int t = 0; t < T; ++t) {
        float ii = volt_b[t * NR + u];         // prefetch; consumed after the chain

        // ---- ballot + projection of current z (= spikes[t-1])
        unsigned long long m = __ballot(z > 0.5f);
        double p = (double)z * wo;
#pragma unroll
        for (int o = 32; o > 0; o >>= 1) p += __shfl_xor(p, o, 64);
        if (lane == 0) { wcnt[wav] = __popcll(m); projp[wav] = p; }
        __syncthreads();                       // A: wcnt + projp ready

        int cnt = 0, base = 0, cnt_lo = 0;
#pragma unroll
        for (int w2 = 0; w2 < 8; ++w2) {
            int c = wcnt[w2];
            if (w2 < wav) base += c;
            if (w2 < 4) cnt_lo += c;
            cnt += c;
        }
        if (z > 0.5f) {
            int pos = base + __popcll(m & ((1ull << lane) - 1ull));
            list[pos] = u;                     // ascending u order
        }
        if (u >= cnt) list[u] = NR;            // refresh stale slots -> zero row
        if (u == 0 && t > 0) {                 // EMA for t-1, overlapped
            double pr = bo;
#pragma unroll
            for (int w2 = 0; w2 < 8; ++w2) pr += projp[w2];
            ema = 0.8 * ema + 0.2 * pr;
            pred[t - 1] = (float)ema;
        }
        __syncthreads();                       // B: list ready

        // ---- double-buffered pipelined two-panel chain (bit-exact order)
        float s1 = 0.f, s2 = 0.f;
        if (cnt > 0) {
            float bufA[G], bufB[G];
            loadg(bufA, list, 0, w_ws, u);
            int g = 0;
            while (true) {
                int k0 = g * G;
                if (k0 + G < cnt) loadg(bufB, list, k0 + G, w_ws, u);
                sumg(bufA, k0, cnt_lo, s1, s2);
                ++g; k0 = g * G;
                if (k0 >= cnt) break;
                if (k0 + G < cnt) loadg(bufA, list, k0 + G, w_ws, u);
                sumg(bufB, k0, cnt_lo, s1, s2);
                ++g;
                if (g * G >= cnt) break;
            }
        }
        float rec = __fadd_rn(s1, s2);         // panel join (one rounded add)

        // ---- LIF update (reference op order, no contraction)
        float it = __fadd_rn(ii, rec);
        float m1 = mul_nofma(decay, v);
        float t2 = __fadd_rn(m1, it);
        float vn = __fsub_rn(t2, z);
        float zn = (vn > 1.0f) ? 1.0f : 0.0f;
        volt_b[t * NR + u] = vn;
        spk_b[t * NR + u]  = zn;
        v = vn; z = zn;
    }

    // ---- final pred[T-1]
    {
        double p = (double)z * wo;
#pragma unroll
        for (int o = 32; o > 0; o >>= 1) p += __shfl_xor(p, o, 64);
        if (lane == 0) projp[wav] = p;
        __syncthreads();
        if (u == 0) {
            double pr = bo;
#pragma unroll
            for (int w2 = 0; w2 < 8; ++w2) pr += projp[w2];
            ema = 0.8 * ema + 0.2 * pr;
            pred[T - 1] = (float)ema;
        }
    }
}

// ---------------- Fallback: verified round-13 scan (no d_ws needed)
__global__ __launch_bounds__(512) void k_scan_ref(const float* __restrict__ w_rec,
                                                  const float* __restrict__ w_out,
                                                  const float* __restrict__ b_out,
                                                  float* __restrict__ out) {
    const int b = blockIdx.x;
    const int u = threadIdx.x;
    const int wav = u >> 6, lane = u & 63;

    float* __restrict__ volt_b = out + (long)b * (T * NR);
    float* __restrict__ spk_b  = out + (long)B * T * NR + (long)b * (T * NR);
    float* __restrict__ pred   = out + 2L * B * T * NR;

    __shared__ __align__(16) int list[NR];
    __shared__ int wcnt[8];
    __shared__ double projp[8];

    float v = 0.f, z = 0.f;
    const float decay = 0.951229424500714f;
    const double wo = (double)w_out[u];
    const double bo = (double)b_out[0];
    double ema = 0.0;

    for (int t = 0; t < T; ++t) {
        unsigned long long m = __ballot(z > 0.5f);
        if (lane == 0) wcnt[wav] = __popcll(m);
        __syncthreads();
        int cnt = 0, base = 0;
#pragma unroll
        for (int w2 = 0; w2 < 8; ++w2) {
            int c = wcnt[w2];
            if (w2 < wav) base += c;
            cnt += c;
        }
        if (z > 0.5f) {
            int pos = base + __popcll(m & ((1ull << lane) - 1ull));
            list[pos] = u;
        }
        float ii = volt_b[t * NR + u];
        __syncthreads();

        float s1 = 0.f, s2 = 0.f;
        int k = 0;
        for (; k + 8 <= cnt; k += 8) {
            int4 ja = *(const int4*)&list[k];
            int4 jb = *(const int4*)&list[k + 4];
            int j0 = __builtin_amdgcn_readfirstlane(ja.x);
            int j1 = __builtin_amdgcn_readfirstlane(ja.y);
            int j2 = __builtin_amdgcn_readfirstlane(ja.z);
            int j3 = __builtin_amdgcn_readfirstlane(ja.w);
            int j4 = __builtin_amdgcn_readfirstlane(jb.x);
            int j5 = __builtin_amdgcn_readfirstlane(jb.y);
            int j6 = __builtin_amdgcn_readfirstlane(jb.z);
            int j7 = __builtin_amdgcn_readfirstlane(jb.w);
            float w0 = w_rec[j0 * NR + u]; if (j0 == u) w0 = 0.f;
            float w1 = w_rec[j1 * NR + u]; if (j1 == u) w1 = 0.f;
            float w2 = w_rec[j2 * NR + u]; if (j2 == u) w2 = 0.f;
            float w3 = w_rec[j3 * NR + u]; if (j3 == u) w3 = 0.f;
            float w4 = w_rec[j4 * NR + u]; if (j4 == u) w4 = 0.f;
            float w5 = w_rec[j5 * NR + u]; if (j5 == u) w5 = 0.f;
            float w6 = w_rec[j6 * NR + u]; if (j6 == u) w6 = 0.f;
            float w7 = w_rec[j7 * NR + u]; if (j7 == u) w7 = 0.f;
            if (j0 < KC) s1 = __fadd_rn(s1, w0); else s2 = __fadd_rn(s2, w0);
            if (j1 < KC) s1 = __fadd_rn(s1, w1); else s2 = __fadd_rn(s2, w1);
            if (j2 < KC) s1 = __fadd_rn(s1, w2); else s2 = __fadd_rn(s2, w2);
            if (j3 < KC) s1 = __fadd_rn(s1, w3); else s2 = __fadd_rn(s2, w3);
            if (j4 < KC) s1 = __fadd_rn(s1, w4); else s2 = __fadd_rn(s2, w4);
            if (j5 < KC) s1 = __fadd_rn(s1, w5); else s2 = __fadd_rn(s2, w5);
            if (j6 < KC) s1 = __fadd_rn(s1, w6); else s2 = __fadd_rn(s2, w6);
            if (j7 < KC) s1 = __fadd_rn(s1, w7); else s2 = __fadd_rn(s2, w7);
        }
        for (; k < cnt; ++k) {
            int j = __builtin_amdgcn_readfirstlane(list[k]);
            float w = w_rec[j * NR + u];
            if (j == u) w = 0.f;
            if (j < KC) s1 = __fadd_rn(s1, w); else s2 = __fadd_rn(s2, w);
        }
        float rec = __fadd_rn(s1, s2);

        float it = __fadd_rn(ii, rec);
        float m1 = mul_nofma(decay, v);
        float t2 = __fadd_rn(m1, it);
        float vn = __fsub_rn(t2, z);
        float zn = (vn > 1.0f) ? 1.0f : 0.0f;
        volt_b[t * NR + u] = vn;
        spk_b[t * NR + u]  = zn;

        double p = (double)zn * wo;
#pragma unroll
        for (int o = 32; o > 0; o >>= 1) p += __shfl_xor(p, o, 64);
        if (lane == 0) projp[wav] = p;
        __syncthreads();
        if (u == 0) {
            double pr = bo;
#pragma unroll
            for (int w2 = 0; w2 < 8; ++w2) pr += projp[w2];
            ema = 0.8 * ema + 0.2 * pr;
            pred[b * T + t] = (float)ema;
        }
        v = vn; z = zn;
    }
}

extern "C" void kernel_launch(void* const* d_in, const int* in_sizes, int n_in,
                              void* d_out, int out_size, void* d_ws, size_t ws_size,
                              hipStream_t stream) {
    const float* inputs = (const float*)d_in[0];
    const float* w_in   = (const float*)d_in[1];
    const float* w_rec  = (const float*)d_in[2];
    const float* w_out  = (const float*)d_in[3];
    const float* b_out  = (const float*)d_in[4];
    float* out = (float*)d_out;

    k_in_gemm<16><<<dim3(B * T / 16), dim3(512), 0, stream>>>(inputs, w_in, out);

    const size_t need = (size_t)(NR + 1) * NR * sizeof(float);
    if (ws_size >= need) {
        float* w_ws = (float*)d_ws;
        k_prep<<<dim3(NR + 1), dim3(512), 0, stream>>>(w_rec, w_ws);
        k_scan<<<dim3(B), dim3(512), 0, stream>>>(w_ws, w_out, b_out, out);
    } else {
        k_scan_ref<<<dim3(B), dim3(512), 0, stream>>>(w_rec, w_out, b_out, out);
    }
}

// Round 16
// 2596.247 us; speedup vs baseline: 3.7672x; 3.7672x over previous
//
#include <hip/hip_runtime.h>

#define NR 512
#define NI 128
#define B 32
#define T 1000
#define G 16          // pipelined load-group width; 2x16 floats stays in VGPRs
#define LA (256 + G)  // per-panel list capacity (incl. permanent pad)
// Locked numeric model (verified PASS rounds 13/14/15):
//  - input GEMM: per element single ascending-i FMA chain.
//  - z @ w_rec_masked: two 256-wide ascending-k chains (OpenBLAS K-panel
//    rebalancing: [0,256)+[256,512)), joined by one rounded add.
//    Binary z => only active rows; masked diag and zero-row pads are exact +0.
//    s1/s2 are independent chains -> panel-separated walk is bit-identical.
//  - elementwise: separate rounded f32 ops ((f32(decay)*v) + i_t) - z.

__device__ __forceinline__ float mul_nofma(float a, float b) {
    float r = a * b;
    asm volatile("" : "+v"(r));
    return r;
}

// ---------------- Kernel 0: masked w_rec copy + zero row into d_ws
__global__ __launch_bounds__(512) void k_prep(const float* __restrict__ w_rec,
                                              float* __restrict__ w_ws) {
    const int r = blockIdx.x, u = threadIdx.x;
    float val = 0.f;
    if (r < NR && r != u) val = w_rec[r * NR + u];
    w_ws[r * NR + u] = val;
}

// ---------------- Kernel 1: i_in = inputs @ w_in -> voltages region of d_out
template <int ROWS>
__global__ __launch_bounds__(512) void k_in_gemm(const float* __restrict__ inputs,
                                                 const float* __restrict__ w_in,
                                                 float* __restrict__ i_in) {
    const int u = threadIdx.x;
    const int r0 = blockIdx.x * ROWS;
    float acc[ROWS];
#pragma unroll
    for (int r = 0; r < ROWS; ++r) acc[r] = 0.f;
    const float* __restrict__ inp = inputs + (long)r0 * NI;
#pragma unroll 4
    for (int i = 0; i < NI; ++i) {
        float w = w_in[i * NR + u];
#pragma unroll
        for (int r = 0; r < ROWS; ++r)
            acc[r] = __builtin_fmaf(inp[r * NI + i], w, acc[r]);   // ascending i, FMA
    }
#pragma unroll
    for (int r = 0; r < ROWS; ++r)
        i_in[(long)(r0 + r) * NR + u] = acc[r];
}

// ---- pipelined helpers: static buffer indexing only (no spill)
__device__ __forceinline__ void loadg(float (&buf)[G], int g, int nlo,
                                      const int* __restrict__ listA,
                                      const int* __restrict__ listB,
                                      const float* __restrict__ w_ws, int u) {
    const int* lp = (g < nlo) ? (listA + g * G) : (listB + (g - nlo) * G);
#pragma unroll
    for (int qq = 0; qq < G / 4; ++qq) {
        int4 jv = *(const int4*)(lp + qq * 4);
        int j0 = __builtin_amdgcn_readfirstlane(jv.x);
        int j1 = __builtin_amdgcn_readfirstlane(jv.y);
        int j2 = __builtin_amdgcn_readfirstlane(jv.z);
        int j3 = __builtin_amdgcn_readfirstlane(jv.w);
        buf[qq * 4 + 0] = w_ws[j0 * NR + u];
        buf[qq * 4 + 1] = w_ws[j1 * NR + u];
        buf[qq * 4 + 2] = w_ws[j2 * NR + u];
        buf[qq * 4 + 3] = w_ws[j3 * NR + u];
    }
}

__device__ __forceinline__ void sumg(const float (&buf)[G], int g, int nlo,
                                     float& s1, float& s2) {
    float& s = (g < nlo) ? s1 : s2;
#pragma unroll
    for (int q = 0; q < G; ++q) s = __fadd_rn(s, buf[q]);
}

// ---------------- Kernel 2: per-batch LIF scan, 2-deep pipelined load groups.
// 32 blocks x 512 threads; 2 barriers/step.
__global__ __launch_bounds__(512) void k_scan(const float* __restrict__ w_ws,
                                              const float* __restrict__ w_out,
                                              const float* __restrict__ b_out,
                                              float* __restrict__ out) {
    const int b = blockIdx.x;
    const int u = threadIdx.x;
    const int wav = u >> 6, lane = u & 63;

    float* __restrict__ volt_b = out + (long)b * (T * NR);                 // also i_in (in-place)
    float* __restrict__ spk_b  = out + (long)B * T * NR + (long)b * (T * NR);
    float* __restrict__ pred   = out + 2L * B * T * NR + (long)b * T;

    __shared__ __align__(16) int listA[LA];
    __shared__ __align__(16) int listB[LA];
    __shared__ int wcnt[8];
    __shared__ double projp[8];

    if (u >= 256 && u < 256 + G) { listA[u] = NR; listB[u] = NR; }  // permanent pads

    float v = 0.f, z = 0.f;
    const float decay = 0.951229424500714f;   // f32 rounding of the python scalar
    const double wo = (double)w_out[u];
    const double bo = (double)b_out[0];
    double ema = 0.0;                          // thread 0's copy is canonical
    __syncthreads();

    for (int t = 0; t < T; ++t) {
        float ii = volt_b[t * NR + u];         // prefetch; consumed after the chain

        // ---- ballot + projection of current z (= spikes[t-1])
        unsigned long long m = __ballot(z > 0.5f);
        double p = (double)z * wo;
#pragma unroll
        for (int o = 32; o > 0; o >>= 1) p += __shfl_xor(p, o, 64);
        if (lane == 0) { wcnt[wav] = __popcll(m); projp[wav] = p; }
        __syncthreads();                       // A: wcnt + projp ready

        const int c0 = wcnt[0], c1 = wcnt[1], c2 = wcnt[2], c3 = wcnt[3];
        const int c4 = wcnt[4], c5 = wcnt[5], c6 = wcnt[6], c7 = wcnt[7];
        const int cnt_lo = c0 + c1 + c2 + c3;
        const int cnt_hi = c4 + c5 + c6 + c7;

        // scatter actives into per-panel lists (ascending u within each panel)
        if (z > 0.5f) {
            int below = __popcll(m & ((1ull << lane) - 1ull));
            if (wav < 4) {
                int pos = (wav > 0 ? c0 : 0) + (wav > 1 ? c1 : 0) + (wav > 2 ? c2 : 0) + below;
                listA[pos] = u;
            } else {
                int pos = (wav > 4 ? c4 : 0) + (wav > 5 ? c5 : 0) + (wav > 6 ? c6 : 0) + below;
                listB[pos] = u;
            }
        }
        // refresh stale slots -> zero row (disjoint from scatter targets)
        if (u < 256) { if (u >= cnt_lo) listA[u] = NR; }
        else         { int x = u - 256; if (x >= cnt_hi) listB[x] = NR; }

        if (u == 0 && t > 0) {                 // EMA for t-1, overlapped with list build
            double pr = bo;
#pragma unroll
            for (int w2 = 0; w2 < 8; ++w2) pr += projp[w2];
            ema = 0.8 * ema + 0.2 * pr;
            pred[t - 1] = (float)ema;
        }
        __syncthreads();                       // B: lists ready

        // ---- two-panel chain, 2-deep pipelined 16-wide groups (bit-exact order)
        const int nlo = (cnt_lo + G - 1) >> 4;
        const int ng  = nlo + ((cnt_hi + G - 1) >> 4);
        float s1 = 0.f, s2 = 0.f;
        if (ng > 0) {
            float bA[G], bB[G];
            loadg(bA, 0, nlo, listA, listB, w_ws, u);
            int g = 0;
            while (true) {
                if (g + 1 < ng) loadg(bB, g + 1, nlo, listA, listB, w_ws, u);
                sumg(bA, g, nlo, s1, s2);
                ++g;
                if (g == ng) break;
                if (g + 1 < ng) loadg(bA, g + 1, nlo, listA, listB, w_ws, u);
                sumg(bB, g, nlo, s1, s2);
                ++g;
                if (g == ng) break;
            }
        }
        float rec = __fadd_rn(s1, s2);         // panel join (one rounded add)

        // ---- LIF update (reference op order, no contraction)
        float it = __fadd_rn(ii, rec);
        float m1 = mul_nofma(decay, v);
        float t2 = __fadd_rn(m1, it);
        float vn = __fsub_rn(t2, z);
        float zn = (vn > 1.0f) ? 1.0f : 0.0f;
        volt_b[t * NR + u] = vn;
        spk_b[t * NR + u]  = zn;
        v = vn; z = zn;
    }

    // ---- final pred[T-1]
    {
        double p = (double)z * wo;
#pragma unroll
        for (int o = 32; o > 0; o >>= 1) p += __shfl_xor(p, o, 64);
        if (lane == 0) projp[wav] = p;
        __syncthreads();
        if (u == 0) {
            double pr = bo;
#pragma unroll
            for (int w2 = 0; w2 < 8; ++w2) pr += projp[w2];
            ema = 0.8 * ema + 0.2 * pr;
            pred[T - 1] = (float)ema;
        }
    }
}

// ---------------- Fallback: verified round-13 scan (no d_ws needed)
__global__ __launch_bounds__(512) void k_scan_ref(const float* __restrict__ w_rec,
                                                  const float* __restrict__ w_out,
                                                  const float* __restrict__ b_out,
                                                  float* __restrict__ out) {
    const int b = blockIdx.x;
    const int u = threadIdx.x;
    const int wav = u >> 6, lane = u & 63;
    const int KC = 256;

    float* __restrict__ volt_b = out + (long)b * (T * NR);
    float* __restrict__ spk_b  = out + (long)B * T * NR + (long)b * (T * NR);
    float* __restrict__ pred   = out + 2L * B * T * NR;

    __shared__ __align__(16) int list[NR];
    __shared__ int wcnt[8];
    __shared__ double projp[8];

    float v = 0.f, z = 0.f;
    const float decay = 0.951229424500714f;
    const double wo = (double)w_out[u];
    const double bo = (double)b_out[0];
    double ema = 0.0;

    for (int t = 0; t < T; ++t) {
        unsigned long long m = __ballot(z > 0.5f);
        if (lane == 0) wcnt[wav] = __popcll(m);
        __syncthreads();
        int cnt = 0, base = 0;
#pragma unroll
        for (int w2 = 0; w2 < 8; ++w2) {
            int c = wcnt[w2];
            if (w2 < wav) base += c;
            cnt += c;
        }
        if (z > 0.5f) {
            int pos = base + __popcll(m & ((1ull << lane) - 1ull));
            list[pos] = u;
        }
        float ii = volt_b[t * NR + u];
        __syncthreads();

        float s1 = 0.f, s2 = 0.f;
        int k = 0;
        for (; k + 8 <= cnt; k += 8) {
            int4 ja = *(const int4*)&list[k];
            int4 jb = *(const int4*)&list[k + 4];
            int j0 = __builtin_amdgcn_readfirstlane(ja.x);
            int j1 = __builtin_amdgcn_readfirstlane(ja.y);
            int j2 = __builtin_amdgcn_readfirstlane(ja.z);
            int j3 = __builtin_amdgcn_readfirstlane(ja.w);
            int j4 = __builtin_amdgcn_readfirstlane(jb.x);
            int j5 = __builtin_amdgcn_readfirstlane(jb.y);
            int j6 = __builtin_amdgcn_readfirstlane(jb.z);
            int j7 = __builtin_amdgcn_readfirstlane(jb.w);
            float w0 = w_rec[j0 * NR + u]; if (j0 == u) w0 = 0.f;
            float w1 = w_rec[j1 * NR + u]; if (j1 == u) w1 = 0.f;
            float w2 = w_rec[j2 * NR + u]; if (j2 == u) w2 = 0.f;
            float w3 = w_rec[j3 * NR + u]; if (j3 == u) w3 = 0.f;
            float w4 = w_rec[j4 * NR + u]; if (j4 == u) w4 = 0.f;
            float w5 = w_rec[j5 * NR + u]; if (j5 == u) w5 = 0.f;
            float w6 = w_rec[j6 * NR + u]; if (j6 == u) w6 = 0.f;
            float w7 = w_rec[j7 * NR + u]; if (j7 == u) w7 = 0.f;
            if (j0 < KC) s1 = __fadd_rn(s1, w0); else s2 = __fadd_rn(s2, w0);
            if (j1 < KC) s1 = __fadd_rn(s1, w1); else s2 = __fadd_rn(s2, w1);
            if (j2 < KC) s1 = __fadd_rn(s1, w2); else s2 = __fadd_rn(s2, w2);
            if (j3 < KC) s1 = __fadd_rn(s1, w3); else s2 = __fadd_rn(s2, w3);
            if (j4 < KC) s1 = __fadd_rn(s1, w4); else s2 = __fadd_rn(s2, w4);
            if (j5 < KC) s1 = __fadd_rn(s1, w5); else s2 = __fadd_rn(s2, w5);
            if (j6 < KC) s1 = __fadd_rn(s1, w6); else s2 = __fadd_rn(s2, w6);
            if (j7 < KC) s1 = __fadd_rn(s1, w7); else s2 = __fadd_rn(s2, w7);
        }
        for (; k < cnt; ++k) {
            int j = __builtin_amdgcn_readfirstlane(list[k]);
            float w = w_rec[j * NR + u];
            if (j == u) w = 0.f;
            if (j < KC) s1 = __fadd_rn(s1, w); else s2 = __fadd_rn(s2, w);
        }
        float rec = __fadd_rn(s1, s2);

        float it = __fadd_rn(ii, rec);
        float m1 = mul_nofma(decay, v);
        float t2 = __fadd_rn(m1, it);
        float vn = __fsub_rn(t2, z);
        float zn = (vn > 1.0f) ? 1.0f : 0.0f;
        volt_b[t * NR + u] = vn;
        spk_b[t * NR + u]  = zn;

        double p = (double)zn * wo;
#pragma unroll
        for (int o = 32; o > 0; o >>= 1) p += __shfl_xor(p, o, 64);
        if (lane == 0) projp[wav] = p;
        __syncthreads();
        if (u == 0) {
            double pr = bo;
#pragma unroll
            for (int w2 = 0; w2 < 8; ++w2) pr += projp[w2];
            ema = 0.8 * ema + 0.2 * pr;
            pred[b * T + t] = (float)ema;
        }
        v = vn; z = zn;
    }
}

extern "C" void kernel_launch(void* const* d_in, const int* in_sizes, int n_in,
                              void* d_out, int out_size, void* d_ws, size_t ws_size,
                              hipStream_t stream) {
    const float* inputs = (const float*)d_in[0];
    const float* w_in   = (const float*)d_in[1];
    const float* w_rec  = (const float*)d_in[2];
    const float* w_out  = (const float*)d_in[3];
    const float* b_out  = (const float*)d_in[4];
    float* out = (float*)d_out;

    k_in_gemm<16><<<dim3(B * T / 16), dim3(512), 0, stream>>>(inputs, w_in, out);

    const size_t need = (size_t)(NR + 1) * NR * sizeof(float);
    if (ws_size >= need) {
        float* w_ws = (float*)d_ws;
        k_prep<<<dim3(NR + 1), dim3(512), 0, stream>>>(w_rec, w_ws);
        k_scan<<<dim3(B), dim3(512), 0, stream>>>(w_ws, w_out, b_out, out);
    } else {
        k_scan_ref<<<dim3(B), dim3(512), 0, stream>>>(w_rec, w_out, b_out, out);
    }
}